// Round 1
// baseline (979.434 us; speedup 1.0000x reference)
//
#include <hip/hip_runtime.h>
#include <hip/hip_bf16.h>

// BERT self-attention fused kernel set for MI355X (gfx950).
// B=4, S=1024, H=1024, NH=16, HD=64.
// Outputs: ctx [B,S,H] fp32, scores (post-mask, pre-softmax) [B*NH,S,S] fp32.

#define BB 4
#define SS 1024
#define HH 1024
#define NHH 16
#define HDD 64
#define BHH (BB*NHH)   // 64
#define MM (BB*SS)     // 4096

typedef __bf16 bf16_t;
typedef __bf16 bf16x8 __attribute__((ext_vector_type(8)));
typedef float f32x4 __attribute__((ext_vector_type(4)));

__device__ __forceinline__ bf16x8 cvt_bf16x8(float4 a, float4 b) {
  bf16x8 r;
  r[0]=(bf16_t)a.x; r[1]=(bf16_t)a.y; r[2]=(bf16_t)a.z; r[3]=(bf16_t)a.w;
  r[4]=(bf16_t)b.x; r[5]=(bf16_t)b.y; r[6]=(bf16_t)b.z; r[7]=(bf16_t)b.w;
  return r;
}

// y = x @ W^T + b, written as bf16 in [BH, S, HD] (split-heads) layout.
// 64x64 output tile per block; 4 waves, each wave 16 rows x 64 cols.
__global__ __launch_bounds__(256) void proj_kernel(
    const float* __restrict__ x,    // [M, H]
    const float* __restrict__ W,    // [H, H], row n = output feature
    const float* __restrict__ bias, // [H]
    bf16_t* __restrict__ out)       // [BH, S, HD]
{
  const int lane   = threadIdx.x & 63;
  const int wave   = threadIdx.x >> 6;
  const int lane16 = lane & 15;
  const int quad   = lane >> 4;
  const int mtile  = blockIdx.y;   // 64 tiles of 64 rows
  const int ntile  = blockIdx.x;   // 16 tiles of 64 cols

  const int row = mtile*64 + wave*16 + lane16;
  const float* xrow = x + (size_t)row*HH + quad*8;
  const float* wbase[4];
#pragma unroll
  for (int nn=0; nn<4; ++nn)
    wbase[nn] = W + (size_t)(ntile*64 + nn*16 + lane16)*HH + quad*8;

  f32x4 acc[4] = {};
  for (int ks=0; ks<HH/32; ++ks) {
    const float* xp = xrow + ks*32;
    bf16x8 afrag = cvt_bf16x8(*(const float4*)xp, *(const float4*)(xp+4));
#pragma unroll
    for (int nn=0; nn<4; ++nn) {
      const float* wp = wbase[nn] + ks*32;
      bf16x8 bfrag = cvt_bf16x8(*(const float4*)wp, *(const float4*)(wp+4));
      acc[nn] = __builtin_amdgcn_mfma_f32_16x16x32_bf16(afrag, bfrag, acc[nn], 0,0,0);
    }
  }

  const int mrow = mtile*64 + wave*16 + quad*4;  // + r
#pragma unroll
  for (int nn=0; nn<4; ++nn) {
    const int n = ntile*64 + nn*16 + lane16;
    const float bn = bias[n];
    const int h = n >> 6, d = n & 63;
#pragma unroll
    for (int r=0; r<4; ++r) {
      const int m_ = mrow + r;
      const int b_ = m_ >> 10, s_ = m_ & (SS-1);
      out[((size_t)(b_*NHH + h)*SS + s_)*HDD + d] = (bf16_t)(acc[nn][r] + bn);
    }
  }
}

// Fused flash-style attention: one block per (q-tile of 64 rows, bh).
// Writes masked pre-softmax scores to global, online softmax, P*V in MFMA.
__global__ __launch_bounds__(256) void attn_kernel(
    const bf16_t* __restrict__ Q,   // [BH,S,HD]
    const bf16_t* __restrict__ K,   // [BH,S,HD]
    const bf16_t* __restrict__ V,   // [BH,S,HD]
    const int*    __restrict__ mask,// [BH,S,S], nonzero -> add -9999
    float* __restrict__ ctx,        // [B,S,H]
    float* __restrict__ scores)     // [BH,S,S]
{
  __shared__ bf16_t VT[64][72];        // V^T tile, padded stride
  __shared__ bf16_t Plds[4][16][72];   // per-wave P round-trip

  const int tid    = threadIdx.x;
  const int lane   = tid & 63, wave = tid >> 6;
  const int lane16 = lane & 15, quad = lane >> 4;
  const int qt = blockIdx.x, bh = blockIdx.y;

  const bf16_t* Qp = Q + (size_t)bh*SS*HDD;
  const bf16_t* Kp = K + (size_t)bh*SS*HDD;
  const bf16_t* Vp = V + (size_t)bh*SS*HDD;

  // Q fragments held in registers for the whole K sweep.
  const int qrow = qt*64 + wave*16 + lane16;
  bf16x8 qa0 = *(const bf16x8*)(Qp + (size_t)qrow*HDD + quad*8);
  bf16x8 qa1 = *(const bf16x8*)(Qp + (size_t)qrow*HDD + 32 + quad*8);

  f32x4 O[4] = {};
  float m_run[4], l_run[4];
#pragma unroll
  for (int r=0;r<4;++r){ m_run[r] = -1e30f; l_run[r] = 0.f; }

  const int srow0 = qt*64 + wave*16 + quad*4; // + r

  // V^T staging assignment: lane-contiguous kk keeps LDS writes ~conflict-free
  const int kk = tid & 63;
  const int dbase = (tid >> 6) * 16;

  for (int kt=0; kt<SS/64; ++kt) {
    __syncthreads();  // protect previous iteration's VT reads
    {
      const bf16_t* vp = Vp + (size_t)(kt*64 + kk)*HDD + dbase;
      bf16x8 v0 = *(const bf16x8*)vp;
      bf16x8 v1 = *(const bf16x8*)(vp+8);
#pragma unroll
      for (int j=0;j<8;++j) VT[dbase+j][kk] = v0[j];
#pragma unroll
      for (int j=0;j<8;++j) VT[dbase+8+j][kk] = v1[j];
    }
    __syncthreads();

    // S-tile = Q K^T
    f32x4 sacc[4] = {};
#pragma unroll
    for (int nn=0; nn<4; ++nn) {
      const bf16_t* kp = Kp + (size_t)(kt*64 + nn*16 + lane16)*HDD + quad*8;
      bf16x8 kb0 = *(const bf16x8*)kp;
      bf16x8 kb1 = *(const bf16x8*)(kp + 32);
      sacc[nn] = __builtin_amdgcn_mfma_f32_16x16x32_bf16(qa0, kb0, sacc[nn], 0,0,0);
      sacc[nn] = __builtin_amdgcn_mfma_f32_16x16x32_bf16(qa1, kb1, sacc[nn], 0,0,0);
    }

    // scale + mask + stream scores out
    float sv[4][4];
#pragma unroll
    for (int nn=0; nn<4; ++nn) {
      const int col = kt*64 + nn*16 + lane16;
#pragma unroll
      for (int r=0; r<4; ++r) {
        const int srow = srow0 + r;
        const size_t idx = ((size_t)bh*SS + srow)*SS + col;
        float v = sacc[nn][r] * 0.125f;
        if (mask[idx] != 0) v += -9999.0f;
        scores[idx] = v;
        sv[nn][r] = v;
      }
    }

    // online softmax (row lives across 16 lanes of a quad)
    float rmax[4];
#pragma unroll
    for (int r=0;r<4;++r) {
      rmax[r] = fmaxf(fmaxf(sv[0][r],sv[1][r]),fmaxf(sv[2][r],sv[3][r]));
      rmax[r] = fmaxf(rmax[r], __shfl_xor(rmax[r],1));
      rmax[r] = fmaxf(rmax[r], __shfl_xor(rmax[r],2));
      rmax[r] = fmaxf(rmax[r], __shfl_xor(rmax[r],4));
      rmax[r] = fmaxf(rmax[r], __shfl_xor(rmax[r],8));
    }
    float alpha[4];
#pragma unroll
    for (int r=0;r<4;++r) {
      const float nm = fmaxf(m_run[r], rmax[r]);
      alpha[r] = __expf(m_run[r] - nm);
      m_run[r] = nm;
    }
#pragma unroll
    for (int nn=0;nn<4;++nn)
#pragma unroll
      for (int r=0;r<4;++r)
        sv[nn][r] = __expf(sv[nn][r] - m_run[r]);

#pragma unroll
    for (int r=0;r<4;++r) {
      float rs = sv[0][r]+sv[1][r]+sv[2][r]+sv[3][r];
      rs += __shfl_xor(rs,1);
      rs += __shfl_xor(rs,2);
      rs += __shfl_xor(rs,4);
      rs += __shfl_xor(rs,8);
      l_run[r] = l_run[r]*alpha[r] + rs;
    }

#pragma unroll
    for (int nn=0;nn<4;++nn)
#pragma unroll
      for (int r=0;r<4;++r)
        O[nn][r] *= alpha[r];

    // P: C-layout -> A-layout via per-wave LDS round trip
#pragma unroll
    for (int nn=0;nn<4;++nn)
#pragma unroll
      for (int r=0;r<4;++r)
        Plds[wave][quad*4+r][nn*16+lane16] = (bf16_t)sv[nn][r];

    bf16x8 pa0 = *(const bf16x8*)&Plds[wave][lane16][quad*8];
    bf16x8 pa1 = *(const bf16x8*)&Plds[wave][lane16][32+quad*8];
#pragma unroll
    for (int nn=0;nn<4;++nn) {
      bf16x8 vb0 = *(const bf16x8*)&VT[nn*16+lane16][quad*8];
      bf16x8 vb1 = *(const bf16x8*)&VT[nn*16+lane16][32+quad*8];
      O[nn] = __builtin_amdgcn_mfma_f32_16x16x32_bf16(pa0, vb0, O[nn], 0,0,0);
      O[nn] = __builtin_amdgcn_mfma_f32_16x16x32_bf16(pa1, vb1, O[nn], 0,0,0);
    }
  }

  // epilogue: normalize and write ctx
  const int b_ = bh / NHH, h_ = bh % NHH;
#pragma unroll
  for (int r=0;r<4;++r) {
    const float inv = 1.0f / l_run[r];
    const int srow = srow0 + r;
#pragma unroll
    for (int nn=0;nn<4;++nn) {
      const int d = nn*16 + lane16;
      ctx[(size_t)(b_*SS + srow)*HH + h_*HDD + d] = O[nn][r] * inv;
    }
  }
}

extern "C" void kernel_launch(void* const* d_in, const int* in_sizes, int n_in,
                              void* d_out, int out_size, void* d_ws, size_t ws_size,
                              hipStream_t stream) {
  const float* q_in = (const float*)d_in[0];
  const float* k_in = (const float*)d_in[1];
  const float* v_in = (const float*)d_in[2];
  const int*   msk  = (const int*)d_in[3];   // bool mask assumed int32
  const float* Wq   = (const float*)d_in[4];
  const float* bq   = (const float*)d_in[5];
  const float* Wk   = (const float*)d_in[6];
  const float* bk   = (const float*)d_in[7];
  const float* Wv   = (const float*)d_in[8];
  const float* bv   = (const float*)d_in[9];

  float* out    = (float*)d_out;
  float* ctx    = out;                       // [B,S,H] = 4M floats
  float* scores = out + (size_t)MM*HH;       // [BH,S,S] = 64M floats

  // workspace: bf16 Q,K,V in [BH,S,HD] layout, 8MB each
  bf16_t* Qw = (bf16_t*)d_ws;
  bf16_t* Kw = Qw + (size_t)BHH*SS*HDD;
  bf16_t* Vw = Kw + (size_t)BHH*SS*HDD;

  dim3 pgrid(HH/64, MM/64);   // (16, 64)
  proj_kernel<<<pgrid, 256, 0, stream>>>(q_in, Wq, bq, Qw);
  proj_kernel<<<pgrid, 256, 0, stream>>>(k_in, Wk, bk, Kw);
  proj_kernel<<<pgrid, 256, 0, stream>>>(v_in, Wv, bv, Vw);

  dim3 agrid(SS/64, BHH);     // (16, 64)
  attn_kernel<<<agrid, 256, 0, stream>>>(Qw, Kw, Vw, msk, ctx, scores);
}

// Round 2
// 657.293 us; speedup vs baseline: 1.4901x; 1.4901x over previous
//
#include <hip/hip_runtime.h>
#include <hip/hip_bf16.h>

// BERT self-attention for MI355X (gfx950).
// B=4, S=1024, H=1024, NH=16, HD=64.
// Outputs: ctx [B,S,H] fp32, scores (post-mask, pre-softmax) [B*NH,S,S] fp32.
//
// Pipeline:
//   1) cvt kernels: fp32 -> bf16 for x_{q,k,v} and W_{q,k,v}
//      (scratch lives in the scores region of d_out -- dead until attn runs)
//   2) batched m97-style MFMA GEMM (grid.z selects q/k/v): y = x @ W^T + b,
//      written bf16 to ws as Q,K in [BH,S,HD]; V transposed to [BH,HD,S]
//   3) barrier-free flash attention: QK^T -> mask+scores out -> online
//      softmax -> P*V (V^T frags straight from global, Plds wave-private)

#define BB 4
#define SS 1024
#define HH 1024
#define NHH 16
#define HDD 64
#define BHH (BB*NHH)   // 64
#define MM (BB*SS)     // 4096

typedef __bf16 bf16_t;
typedef __bf16 bf16x8 __attribute__((ext_vector_type(8)));
typedef float f32x4 __attribute__((ext_vector_type(4)));

#define GL2LDS(g, l) __builtin_amdgcn_global_load_lds( \
    (const __attribute__((address_space(1))) void*)(g), \
    (__attribute__((address_space(3))) void*)(l), 16, 0, 0)

__device__ __forceinline__ bf16x8 cvt_bf16x8(float4 a, float4 b) {
  bf16x8 r;
  r[0]=(bf16_t)a.x; r[1]=(bf16_t)a.y; r[2]=(bf16_t)a.z; r[3]=(bf16_t)a.w;
  r[4]=(bf16_t)b.x; r[5]=(bf16_t)b.y; r[6]=(bf16_t)b.z; r[7]=(bf16_t)b.w;
  return r;
}

// fp32 -> bf16, 8 elems/thread. grid.z selects which tensor.
__global__ __launch_bounds__(256) void cvt_kernel(
    const float* __restrict__ s0, const float* __restrict__ s1,
    const float* __restrict__ s2,
    bf16_t* __restrict__ d0, bf16_t* __restrict__ d1, bf16_t* __restrict__ d2)
{
  const int z = blockIdx.z;
  const float* s = z==0 ? s0 : (z==1 ? s1 : s2);
  bf16_t*      d = z==0 ? d0 : (z==1 ? d1 : d2);
  const size_t i = ((size_t)blockIdx.x*256 + threadIdx.x)*8;
  float4 a = *(const float4*)(s+i);
  float4 b = *(const float4*)(s+i+4);
  *(bf16x8*)(d+i) = cvt_bf16x8(a, b);
}

// m97-style GEMM: C[m,n] = sum_k A[m,k]*W[n,k] + bias[n]  (A:[4096,1024], W:[1024,1024])
// 128x128 tile, BK=32, 256 threads (4 waves, 2x2 of 64x64), global_load_lds w=16.
// z==2 (V) writes transposed [BH,HD,S]; else [BH,S,HD].
__global__ __launch_bounds__(256) void gemm_proj(
    const bf16_t* __restrict__ A0, const bf16_t* __restrict__ A1, const bf16_t* __restrict__ A2,
    const bf16_t* __restrict__ W0, const bf16_t* __restrict__ W1, const bf16_t* __restrict__ W2,
    const float* __restrict__ b0, const float* __restrict__ b1, const float* __restrict__ b2,
    bf16_t* __restrict__ o0, bf16_t* __restrict__ o1, bf16_t* __restrict__ o2)
{
  __shared__ bf16_t As[128*32];
  __shared__ bf16_t Bs[128*32];

  const int z = blockIdx.z;
  const bf16_t* Ap = z==0 ? A0 : (z==1 ? A1 : A2);
  const bf16_t* Wp = z==0 ? W0 : (z==1 ? W1 : W2);
  const float*  bp = z==0 ? b0 : (z==1 ? b1 : b2);
  bf16_t*       op = z==0 ? o0 : (z==1 ? o1 : o2);

  const int tid  = threadIdx.x;
  const int wave = tid >> 6, lane = tid & 63;
  const int lane16 = lane & 15, quad = lane >> 4;
  const int wm = wave >> 1, wn = wave & 1;
  const int nt = blockIdx.x, mt = blockIdx.y;

  // staging: wave w loads 16-row chunks w and w+4 of both tiles
  const int lr = lane >> 2;        // row within chunk
  const int lc = (lane & 3) * 8;   // col offset (8 bf16 = 16B)
  const bf16_t* ag0 = Ap + (size_t)(mt*128 + wave*16 + lr)*HH + lc;
  const bf16_t* ag1 = ag0 + (size_t)64*HH;
  const bf16_t* bg0 = Wp + (size_t)(nt*128 + wave*16 + lr)*HH + lc;
  const bf16_t* bg1 = bg0 + (size_t)64*HH;
  bf16_t* al0 = &As[(wave*16)*32];
  bf16_t* al1 = &As[((wave+4)*16)*32];
  bf16_t* bl0 = &Bs[(wave*16)*32];
  bf16_t* bl1 = &Bs[((wave+4)*16)*32];

  f32x4 acc[4][4] = {};

  for (int ks = 0; ks < HH/32; ++ks) {
    __syncthreads();
    GL2LDS(ag0, al0); GL2LDS(ag1, al1);
    GL2LDS(bg0, bl0); GL2LDS(bg1, bl1);
    __syncthreads();

    bf16x8 af[4], bf_[4];
#pragma unroll
    for (int mi=0; mi<4; ++mi)
      af[mi] = *(const bf16x8*)&As[(wm*64 + mi*16 + lane16)*32 + quad*8];
#pragma unroll
    for (int ni=0; ni<4; ++ni)
      bf_[ni] = *(const bf16x8*)&Bs[(wn*64 + ni*16 + lane16)*32 + quad*8];
#pragma unroll
    for (int mi=0; mi<4; ++mi)
#pragma unroll
      for (int ni=0; ni<4; ++ni)
        acc[mi][ni] = __builtin_amdgcn_mfma_f32_16x16x32_bf16(af[mi], bf_[ni], acc[mi][ni], 0,0,0);

    ag0 += 32; ag1 += 32; bg0 += 32; bg1 += 32;
  }

  // epilogue
#pragma unroll
  for (int ni=0; ni<4; ++ni) {
    const int n = nt*128 + wn*64 + ni*16 + lane16;
    const float bn = bp[n];
    const int h = n >> 6, d = n & 63;
#pragma unroll
    for (int mi=0; mi<4; ++mi) {
#pragma unroll
      for (int r=0; r<4; ++r) {
        const int m = mt*128 + wm*64 + mi*16 + quad*4 + r;
        const int b_ = m >> 10, s_ = m & (SS-1);
        const float v = acc[mi][ni][r] + bn;
        if (z != 2)
          op[((size_t)(b_*NHH + h)*SS + s_)*HDD + d] = (bf16_t)v;   // [BH,S,HD]
        else
          op[((size_t)(b_*NHH + h)*HDD + d)*SS + s_] = (bf16_t)v;   // [BH,HD,S]
      }
    }
  }
}

// Barrier-free fused attention. One block per (64-row q-tile, bh); 4 waves,
// each wave owns 16 q-rows. V^T frags straight from global; mask prefetched.
__global__ __launch_bounds__(256) void attn_kernel(
    const bf16_t* __restrict__ Q,   // [BH,S,HD]
    const bf16_t* __restrict__ K,   // [BH,S,HD]
    const bf16_t* __restrict__ VT,  // [BH,HD,S]
    const int*    __restrict__ mask,// [BH,S,S], nonzero -> add -9999
    float* __restrict__ ctx,        // [B,S,H]
    float* __restrict__ scores)     // [BH,S,S]
{
  __shared__ bf16_t Plds[4][2][16][72];  // wave-private, double-buffered by kt parity

  const int tid    = threadIdx.x;
  const int lane   = tid & 63, wave = tid >> 6;
  const int lane16 = lane & 15, quad = lane >> 4;
  const int qt = blockIdx.x, bh = blockIdx.y;

  const bf16_t* Qp  = Q  + (size_t)bh*SS*HDD;
  const bf16_t* Kp  = K  + (size_t)bh*SS*HDD;
  const bf16_t* VTp = VT + (size_t)bh*HDD*SS;

  const int qrow = qt*64 + wave*16 + lane16;
  bf16x8 qa0 = *(const bf16x8*)(Qp + (size_t)qrow*HDD + quad*8);
  bf16x8 qa1 = *(const bf16x8*)(Qp + (size_t)qrow*HDD + 32 + quad*8);

  f32x4 O[4] = {};
  float m_run[4], l_run[4];
#pragma unroll
  for (int r=0;r<4;++r){ m_run[r] = -1e30f; l_run[r] = 0.f; }

  const int srow0 = qt*64 + wave*16 + quad*4; // + r
  size_t sbase[4];
#pragma unroll
  for (int r=0;r<4;++r) sbase[r] = ((size_t)bh*SS + srow0 + r)*SS;

  // mask prefetch: cur holds values for iteration kt
  int mcur[4][4];
#pragma unroll
  for (int nn=0;nn<4;++nn)
#pragma unroll
    for (int r=0;r<4;++r)
      mcur[nn][r] = mask[sbase[r] + nn*16 + lane16];

  for (int kt=0; kt<SS/64; ++kt) {
    int mnext[4][4];
    if (kt < SS/64 - 1) {
#pragma unroll
      for (int nn=0;nn<4;++nn)
#pragma unroll
        for (int r=0;r<4;++r)
          mnext[nn][r] = mask[sbase[r] + (kt+1)*64 + nn*16 + lane16];
    }

    // S-tile = Q K^T
    f32x4 sacc[4] = {};
#pragma unroll
    for (int nn=0; nn<4; ++nn) {
      const bf16_t* kp = Kp + (size_t)(kt*64 + nn*16 + lane16)*HDD + quad*8;
      bf16x8 kb0 = *(const bf16x8*)kp;
      bf16x8 kb1 = *(const bf16x8*)(kp + 32);
      sacc[nn] = __builtin_amdgcn_mfma_f32_16x16x32_bf16(qa0, kb0, sacc[nn], 0,0,0);
      sacc[nn] = __builtin_amdgcn_mfma_f32_16x16x32_bf16(qa1, kb1, sacc[nn], 0,0,0);
    }

    // scale + mask + stream scores out
    float sv[4][4];
#pragma unroll
    for (int nn=0; nn<4; ++nn) {
      const int col = kt*64 + nn*16 + lane16;
#pragma unroll
      for (int r=0; r<4; ++r) {
        float v = sacc[nn][r] * 0.125f;
        if (mcur[nn][r] != 0) v += -9999.0f;
        scores[sbase[r] + col] = v;
        sv[nn][r] = v;
      }
    }

    // online softmax (row lives across 16 lanes of a quad)
    float rmax[4];
#pragma unroll
    for (int r=0;r<4;++r) {
      rmax[r] = fmaxf(fmaxf(sv[0][r],sv[1][r]),fmaxf(sv[2][r],sv[3][r]));
      rmax[r] = fmaxf(rmax[r], __shfl_xor(rmax[r],1));
      rmax[r] = fmaxf(rmax[r], __shfl_xor(rmax[r],2));
      rmax[r] = fmaxf(rmax[r], __shfl_xor(rmax[r],4));
      rmax[r] = fmaxf(rmax[r], __shfl_xor(rmax[r],8));
    }
    float alpha[4];
#pragma unroll
    for (int r=0;r<4;++r) {
      const float nm = fmaxf(m_run[r], rmax[r]);
      alpha[r] = __expf(m_run[r] - nm);
      m_run[r] = nm;
    }
#pragma unroll
    for (int nn=0;nn<4;++nn)
#pragma unroll
      for (int r=0;r<4;++r)
        sv[nn][r] = __expf(sv[nn][r] - m_run[r]);

#pragma unroll
    for (int r=0;r<4;++r) {
      float rs = sv[0][r]+sv[1][r]+sv[2][r]+sv[3][r];
      rs += __shfl_xor(rs,1);
      rs += __shfl_xor(rs,2);
      rs += __shfl_xor(rs,4);
      rs += __shfl_xor(rs,8);
      l_run[r] = l_run[r]*alpha[r] + rs;
    }

#pragma unroll
    for (int nn=0;nn<4;++nn)
#pragma unroll
      for (int r=0;r<4;++r)
        O[nn][r] *= alpha[r];

    // P: C-layout -> A-layout via wave-private LDS round trip (no barrier)
    const int pb = kt & 1;
#pragma unroll
    for (int nn=0;nn<4;++nn)
#pragma unroll
      for (int r=0;r<4;++r)
        Plds[wave][pb][quad*4+r][nn*16+lane16] = (bf16_t)sv[nn][r];

    bf16x8 pa0 = *(const bf16x8*)&Plds[wave][pb][lane16][quad*8];
    bf16x8 pa1 = *(const bf16x8*)&Plds[wave][pb][lane16][32+quad*8];

    // P * V via V^T rows from global (L2-resident, 8MB)
#pragma unroll
    for (int nn=0;nn<4;++nn) {
      const bf16_t* vp = VTp + (size_t)(nn*16 + lane16)*SS + kt*64 + quad*8;
      bf16x8 vb0 = *(const bf16x8*)vp;
      bf16x8 vb1 = *(const bf16x8*)(vp + 32);
      O[nn] = __builtin_amdgcn_mfma_f32_16x16x32_bf16(pa0, vb0, O[nn], 0,0,0);
      O[nn] = __builtin_amdgcn_mfma_f32_16x16x32_bf16(pa1, vb1, O[nn], 0,0,0);
    }

#pragma unroll
    for (int nn=0;nn<4;++nn)
#pragma unroll
      for (int r=0;r<4;++r)
        mcur[nn][r] = mnext[nn][r];
  }

  // epilogue: normalize and write ctx
  const int b_ = bh / NHH, h_ = bh % NHH;
#pragma unroll
  for (int r=0;r<4;++r) {
    const float inv = 1.0f / l_run[r];
    const int srow = srow0 + r;
#pragma unroll
    for (int nn=0;nn<4;++nn) {
      const int d = nn*16 + lane16;
      ctx[(size_t)(b_*SS + srow)*HH + h_*HDD + d] = O[nn][r] * inv;
    }
  }
}

extern "C" void kernel_launch(void* const* d_in, const int* in_sizes, int n_in,
                              void* d_out, int out_size, void* d_ws, size_t ws_size,
                              hipStream_t stream) {
  const float* q_in = (const float*)d_in[0];
  const float* k_in = (const float*)d_in[1];
  const float* v_in = (const float*)d_in[2];
  const int*   msk  = (const int*)d_in[3];
  const float* Wq   = (const float*)d_in[4];
  const float* bq   = (const float*)d_in[5];
  const float* Wk   = (const float*)d_in[6];
  const float* bk   = (const float*)d_in[7];
  const float* Wv   = (const float*)d_in[8];
  const float* bv   = (const float*)d_in[9];

  float* out    = (float*)d_out;
  float* ctx    = out;                       // [B,S,H] = 4M floats
  float* scores = out + (size_t)MM*HH;       // [BH,S,S] = 64M floats

  // bf16 scratch inside the (not-yet-written) scores region: 30 MB of 256 MB
  bf16_t* xq_b = (bf16_t*)scores;
  bf16_t* xk_b = xq_b + (size_t)MM*HH;       // +4M elems
  bf16_t* xv_b = xk_b + (size_t)MM*HH;
  bf16_t* wq_b = xv_b + (size_t)MM*HH;
  bf16_t* wk_b = wq_b + (size_t)HH*HH;
  bf16_t* wv_b = wk_b + (size_t)HH*HH;

  // ws: bf16 Q,K [BH,S,HD] and V^T [BH,HD,S], 8MB each
  bf16_t* Qw = (bf16_t*)d_ws;
  bf16_t* Kw = Qw + (size_t)BHH*SS*HDD;
  bf16_t* Vw = Kw + (size_t)BHH*SS*HDD;

  // 1) convert inputs+weights to bf16
  cvt_kernel<<<dim3(MM*HH/(256*8), 1, 3), 256, 0, stream>>>(q_in, k_in, v_in, xq_b, xk_b, xv_b);
  cvt_kernel<<<dim3(HH*HH/(256*8), 1, 3), 256, 0, stream>>>(Wq, Wk, Wv, wq_b, wk_b, wv_b);

  // 2) batched projection GEMMs (z: 0=Q, 1=K, 2=V-transposed)
  gemm_proj<<<dim3(HH/128, MM/128, 3), 256, 0, stream>>>(
      xq_b, xk_b, xv_b, wq_b, wk_b, wv_b, bq, bk, bv, Qw, Kw, Vw);

  // 3) fused attention
  attn_kernel<<<dim3(SS/64, BHH), 256, 0, stream>>>(Qw, Kw, Vw, msk, ctx, scores);
}